// Round 2
// baseline (198.933 us; speedup 1.0000x reference)
//
#include <hip/hip_runtime.h>

// out[b,o] = sum_{k<4} w[o*4+k] * x[b, o*4+k] + t[b] * tw[o]
// B=1024, NUM_OUT=8192, BF=4, NUM_IN=32768. All fp32.
// Minimum traffic: 128 MiB x-read + 32 MiB out-write -> ~27-30 us floor at ~6 TB/s.
// 4 outputs/thread -> 16B nt out store, float4 tw load. Native ext_vector_type
// (not HIP_vector_type) so __builtin_nontemporal_store accepts it.

constexpr int BATCH   = 1024;
constexpr int NUM_OUT = 8192;
constexpr int OUT4_PER_ROW = NUM_OUT / 4;   // 2048 float4 per batch row

typedef float f32x4 __attribute__((ext_vector_type(4)));

__global__ __launch_bounds__(256) void DendriticBranchLayerSparse_62689342652745_kernel(
    const f32x4* __restrict__ x4,       // [B * 8192] float4 groups (one group = one output)
    const float* __restrict__ t,        // [B]
    const f32x4* __restrict__ w4,       // [8192] float4 groups (one per output)
    const f32x4* __restrict__ tw4,      // [2048] float4 view of tw[8192]
    f32x4* __restrict__ out4)           // [B * 2048]
{
    const int gid = blockIdx.x * blockDim.x + threadIdx.x;  // one out-quad (4 outputs)
    const int b   = gid >> 11;            // gid / 2048
    const int o4  = gid & (OUT4_PER_ROW - 1);
    const int o   = o4 * 4;               // first output index of this quad

    // x groups for outputs o..o+3 of row b start at float4 index b*8192 + o == gid*4
    const size_t xbase = (size_t)gid * 4;
    const f32x4 x0 = x4[xbase + 0];
    const f32x4 x1 = x4[xbase + 1];
    const f32x4 x2 = x4[xbase + 2];
    const f32x4 x3 = x4[xbase + 3];

    const f32x4 w0 = w4[o + 0];
    const f32x4 w1 = w4[o + 1];
    const f32x4 w2 = w4[o + 2];
    const f32x4 w3 = w4[o + 3];

    const float tb  = t[b];
    const f32x4 twv = tw4[o4];

    f32x4 r;
    r.x = x0.x * w0.x + x0.y * w0.y + x0.z * w0.z + x0.w * w0.w + tb * twv.x;
    r.y = x1.x * w1.x + x1.y * w1.y + x1.z * w1.z + x1.w * w1.w + tb * twv.y;
    r.z = x2.x * w2.x + x2.y * w2.y + x2.z * w2.z + x2.w * w2.w + tb * twv.z;
    r.w = x3.x * w3.x + x3.y * w3.y + x3.z * w3.z + x3.w * w3.w + tb * twv.w;

    // Non-temporal: out is write-once; keep it from evicting the L3-resident x.
    __builtin_nontemporal_store(r, &out4[gid]);
}

extern "C" void kernel_launch(void* const* d_in, const int* in_sizes, int n_in,
                              void* d_out, int out_size, void* d_ws, size_t ws_size,
                              hipStream_t stream) {
    const f32x4* x4  = (const f32x4*)d_in[0];   // [1024, 32768] fp32
    const float* t   = (const float*)d_in[1];   // [1024]
    const f32x4* w4  = (const f32x4*)d_in[2];   // [32768] fp32
    const f32x4* tw4 = (const f32x4*)d_in[3];   // [8192, 1] fp32
    f32x4* out4 = (f32x4*)d_out;                // [1024, 8192] fp32

    const int total_quads = BATCH * OUT4_PER_ROW; // 2,097,152
    const int block = 256;
    const int grid  = total_quads / block;        // 8192

    DendriticBranchLayerSparse_62689342652745_kernel<<<grid, block, 0, stream>>>(
        x4, t, w4, tw4, out4);
}